// Round 3
// baseline (2226.000 us; speedup 1.0000x reference)
//
#include <hip/hip_runtime.h>
#include <math.h>

// Problem constants (from reference)
constexpr int SEQ   = 2048;   // L
constexpr int DMODEL= 512;
constexpr int NLAYER= 8;
constexpr int DSTATE= 16;
constexpr int DINNER= 1024;
constexpr int DTRANK= 32;
constexpr int NVOCAB= 4096;
constexpr int XDIM  = DTRANK + 2*DSTATE;  // 64
constexpr int NC    = 32;                 // scan sequence-chunks
constexpr int CHUNK = SEQ / NC;           // 64
constexpr int NCH   = DINNER * DSTATE;    // 16384 scan channels

// ---------------------------------------------------------------------------
// Embedding: h[l,d] = emb[ids[l],d] + pos[l,d]
__global__ __launch_bounds__(256) void k_embed(const int* __restrict__ ids,
    const float* __restrict__ emb, const float* __restrict__ pos,
    float* __restrict__ h) {
  int t = blockIdx.x*256 + threadIdx.x;           // over SEQ*DMODEL
  int l = t >> 9;                                  // /512
  int d = t & 511;
  h[t] = emb[(size_t)ids[l]*DMODEL + d] + pos[t];
}

// ---------------------------------------------------------------------------
// RMSNorm: one block per row of 512
__global__ __launch_bounds__(256) void k_rmsnorm(const float* __restrict__ in,
    const float* __restrict__ w, float* __restrict__ out) {
  int row = blockIdx.x;
  int tid = threadIdx.x;
  const float2* r = reinterpret_cast<const float2*>(in + (size_t)row*DMODEL);
  float2 v = r[tid];
  float ss = v.x*v.x + v.y*v.y;
  #pragma unroll
  for (int o = 32; o >= 1; o >>= 1) ss += __shfl_xor(ss, o);
  __shared__ float sm[4];
  if ((tid & 63) == 0) sm[tid >> 6] = ss;
  __syncthreads();
  float tot = sm[0] + sm[1] + sm[2] + sm[3];
  float scale = rsqrtf(tot * (1.0f/DMODEL) + 1e-6f);
  float2 wv = reinterpret_cast<const float2*>(w)[tid];
  float2 o2;
  o2.x = v.x * scale * wv.x;
  o2.y = v.y * scale * wv.y;
  reinterpret_cast<float2*>(out + (size_t)row*DMODEL)[tid] = o2;
}

// ---------------------------------------------------------------------------
// Tiled f32 GEMM, C[M,N] (+)= A[M,K] * B[N,K]^T  (both operands K-contiguous)
// block = 256 threads (16x16), each thread computes (BM/16)x(BN/16) outputs.
template<int BM, int BN, int BK, bool ACC>
__global__ __launch_bounds__(256) void gemm_nt(const float* __restrict__ A,
    const float* __restrict__ Bw, float* __restrict__ C,
    int M, int N, int K) {
  constexpr int TM = BM/16, TN = BN/16;
  __shared__ float As[BK][BM+4];
  __shared__ float Bs[BK][BN+4];
  const int tid = threadIdx.x;
  const int tx = tid & 15, ty = tid >> 4;
  const int m0 = blockIdx.y * BM;
  const int n0 = blockIdx.x * BN;

  float acc[TM][TN];
  #pragma unroll
  for (int i = 0; i < TM; ++i)
    #pragma unroll
    for (int j = 0; j < TN; ++j) acc[i][j] = 0.f;

  for (int kt = 0; kt < K; kt += BK) {
    constexpr int A4 = BM*BK/4;
    #pragma unroll
    for (int i = 0; i < A4/256; ++i) {
      int idx = i*256 + tid;
      int row = idx / (BK/4);
      int v   = idx % (BK/4);
      float4 val = *reinterpret_cast<const float4*>(
          &A[(size_t)(m0+row)*K + kt + v*4]);
      As[v*4+0][row] = val.x;
      As[v*4+1][row] = val.y;
      As[v*4+2][row] = val.z;
      As[v*4+3][row] = val.w;
    }
    constexpr int B4 = BN*BK/4;
    #pragma unroll
    for (int i = 0; i < B4/256; ++i) {
      int idx = i*256 + tid;
      int row = idx / (BK/4);
      int v   = idx % (BK/4);
      float4 val = *reinterpret_cast<const float4*>(
          &Bw[(size_t)(n0+row)*K + kt + v*4]);
      Bs[v*4+0][row] = val.x;
      Bs[v*4+1][row] = val.y;
      Bs[v*4+2][row] = val.z;
      Bs[v*4+3][row] = val.w;
    }
    __syncthreads();

    #pragma unroll
    for (int k = 0; k < BK; ++k) {
      float a[TM], b[TN];
      #pragma unroll
      for (int i4 = 0; i4 < TM/4; ++i4) {
        float4 t4 = *reinterpret_cast<const float4*>(&As[k][ty*TM + i4*4]);
        a[i4*4+0] = t4.x; a[i4*4+1] = t4.y; a[i4*4+2] = t4.z; a[i4*4+3] = t4.w;
      }
      #pragma unroll
      for (int j4 = 0; j4 < TN/4; ++j4) {
        float4 t4 = *reinterpret_cast<const float4*>(&Bs[k][tx*TN + j4*4]);
        b[j4*4+0] = t4.x; b[j4*4+1] = t4.y; b[j4*4+2] = t4.z; b[j4*4+3] = t4.w;
      }
      #pragma unroll
      for (int i = 0; i < TM; ++i)
        #pragma unroll
        for (int j = 0; j < TN; ++j)
          acc[i][j] = fmaf(a[i], b[j], acc[i][j]);
    }
    __syncthreads();
  }

  #pragma unroll
  for (int i = 0; i < TM; ++i) {
    size_t row = (size_t)(m0 + ty*TM + i);
    float* crow = C + row*N + n0 + tx*TN;
    #pragma unroll
    for (int j4 = 0; j4 < TN/4; ++j4) {
      float4 v;
      if (ACC) {
        v = *reinterpret_cast<float4*>(&crow[j4*4]);
        v.x += acc[i][j4*4+0]; v.y += acc[i][j4*4+1];
        v.z += acc[i][j4*4+2]; v.w += acc[i][j4*4+3];
      } else {
        v = make_float4(acc[i][j4*4+0], acc[i][j4*4+1],
                        acc[i][j4*4+2], acc[i][j4*4+3]);
      }
      *reinterpret_cast<float4*>(&crow[j4*4]) = v;
    }
  }
}

// ---------------------------------------------------------------------------
// Depthwise causal conv (D_CONV=4) + bias + SiLU.  xi = xz[:, 0:DINNER]
__global__ __launch_bounds__(256) void k_conv_silu(const float* __restrict__ xz,
    const float* __restrict__ cw, const float* __restrict__ cb,
    float* __restrict__ u) {
  int t = blockIdx.x*256 + threadIdx.x;           // over SEQ*DINNER
  int l = t >> 10;
  int c = t & 1023;
  float4 w = reinterpret_cast<const float4*>(cw)[c];
  float acc = cb[c];
  const float* xi = xz + c;                        // row stride 2*DINNER
  if (l >= 3) acc = fmaf(xi[(size_t)(l-3)*2*DINNER], w.x, acc);
  if (l >= 2) acc = fmaf(xi[(size_t)(l-2)*2*DINNER], w.y, acc);
  if (l >= 1) acc = fmaf(xi[(size_t)(l-1)*2*DINNER], w.z, acc);
  acc = fmaf(xi[(size_t)l*2*DINNER], w.w, acc);
  u[t] = acc / (1.f + __expf(-acc));               // silu
}

// ---------------------------------------------------------------------------
// Transpose BOTH skinny weights for ALL layers in one dispatch (hoisted out
// of the layer loop).  Per layer:
//   xwT[k*64+e]    = xw[e*DINNER+k]     (64 x 1024 -> 1024 x 64)
//   dtwT[k*1024+d] = dw[d*DTRANK+k]     (1024 x 32 -> 32 x 1024)
__global__ __launch_bounds__(256) void k_transpose_w_all(
    const float* __restrict__ xw, const float* __restrict__ dw,
    float* __restrict__ xwT, float* __restrict__ dtwT) {
  constexpr int PER = XDIM*DINNER + DTRANK*DINNER;   // 98304 per layer
  int t = blockIdx.x*256 + threadIdx.x;
  int layer = t / PER;
  int r = t - layer*PER;
  if (r < XDIM*DINNER) {
    int k = r >> 6, e = r & 63;
    xwT[(size_t)layer*XDIM*DINNER + r] =
        xw[(size_t)layer*XDIM*DINNER + (size_t)e*DINNER + k];
  } else {
    int r2 = r - XDIM*DINNER;
    int k = r2 >> 10, d = r2 & 1023;
    dtwT[(size_t)layer*DTRANK*DINNER + r2] =
        dw[(size_t)layer*DINNER*DTRANK + (size_t)d*DTRANK + k];
  }
}

// ---------------------------------------------------------------------------
// x_proj: xdbl[l,e] = dot(u[l,:], xw[e,:])   (one wave per row, lane = e)
__global__ __launch_bounds__(256) void k_xproj(const float* __restrict__ u,
    const float* __restrict__ xwT, float* __restrict__ xdbl) {
  int gt = blockIdx.x*256 + threadIdx.x;
  int l = gt >> 6;
  int e = gt & 63;
  const float4* ur = reinterpret_cast<const float4*>(u + (size_t)l*DINNER);
  float acc = 0.f;
  #pragma unroll 4
  for (int k4 = 0; k4 < DINNER/4; ++k4) {
    float4 uu = ur[k4];                            // broadcast across wave
    const float* wp = xwT + k4*4*64 + e;           // coalesced across lanes
    acc = fmaf(uu.x, wp[0],   acc);
    acc = fmaf(uu.y, wp[64],  acc);
    acc = fmaf(uu.z, wp[128], acc);
    acc = fmaf(uu.w, wp[192], acc);
  }
  xdbl[gt] = acc;
}

// ---------------------------------------------------------------------------
// FUSED delta-projection + transpose (replaces k_delta + k_transpose3).
// Per 32x32 (l,d) tile:
//   delta[l,d] = softplus(dot(xdbl[l,0:32], dtwT[:,d]) + db[d])
// then writes [d][l]-layout scan operands:
//   dT = delta^T, duT = (delta*u)^T, udT = (u*Dp[d])^T, zT = z^T
__global__ __launch_bounds__(256) void k_delta_t(
    const float* __restrict__ xdbl, const float* __restrict__ dtwT,
    const float* __restrict__ db, const float* __restrict__ u,
    const float* __restrict__ xz, const float* __restrict__ Dp,
    float* __restrict__ dT, float* __restrict__ duT,
    float* __restrict__ udT, float* __restrict__ zT) {
  __shared__ float xs[32][33];   // xdbl[l][k], k = 0..31 (dt part)
  __shared__ float wt[32][33];   // dtwT[k][d]
  __shared__ float td[32][33];   // delta[l][d]
  __shared__ float tu[32][33];   // u[l][d]
  __shared__ float tz[32][33];   // z[l][d]
  int l0 = blockIdx.x*32, d0 = blockIdx.y*32;
  int tx = threadIdx.x & 31;
  int ty = threadIdx.x >> 5;     // 0..7
  #pragma unroll
  for (int j = 0; j < 32; j += 8) {
    int l = l0 + ty + j;
    xs[ty+j][tx] = xdbl[(size_t)l*XDIM + tx];
    wt[ty+j][tx] = dtwT[(size_t)(ty+j)*DINNER + d0 + tx];
    tu[ty+j][tx] = u[(size_t)l*DINNER + d0 + tx];
    tz[ty+j][tx] = xz[(size_t)l*2*DINNER + DINNER + d0 + tx];
  }
  __syncthreads();
  float bd = db[d0 + tx];
  #pragma unroll
  for (int j = 0; j < 32; j += 8) {
    int lr = ty + j;
    float acc = bd;
    #pragma unroll
    for (int k = 0; k < 32; ++k) acc = fmaf(xs[lr][k], wt[k][tx], acc);
    td[lr][tx] = (acc > 20.f) ? acc : log1pf(expf(acc));
  }
  __syncthreads();
  #pragma unroll
  for (int j = 0; j < 32; j += 8) {
    int d = d0 + ty + j, l = l0 + tx;
    float dv = td[tx][ty+j], uv = tu[tx][ty+j];
    size_t o = (size_t)d*SEQ + l;
    dT[o]  = dv;
    duT[o] = dv * uv;
    udT[o] = uv * Dp[d];
    zT[o]  = tz[tx][ty+j];
  }
}

// ---------------------------------------------------------------------------
// Chunked selective scan, phase 1: per chunk compute P = prod(dA) and
// S = local final state (h_in = 0).  Lane = (d, s): s = lane&15.
__global__ __launch_bounds__(256) void k_scan_p1(const float* __restrict__ dT,
    const float* __restrict__ duT, const float* __restrict__ xdbl,
    const float* __restrict__ alog, float* __restrict__ P, float* __restrict__ S) {
  int tid = threadIdx.x;
  int s = tid & 15;
  int d = blockIdx.x*16 + (tid >> 4);
  int c = blockIdx.y;
  float A = -__expf(alog[d*DSTATE + s]);
  float hs = 0.f, Pp = 1.f;
  const float4* dr = reinterpret_cast<const float4*>(dT  + (size_t)d*SEQ + c*CHUNK);
  const float4* br = reinterpret_cast<const float4*>(duT + (size_t)d*SEQ + c*CHUNK);
  const float* Bp = xdbl + (size_t)c*CHUNK*XDIM + DTRANK + s;
  for (int q = 0; q < CHUNK/4; ++q) {
    float dv[4], bv[4];
    *reinterpret_cast<float4*>(dv) = dr[q];
    *reinterpret_cast<float4*>(bv) = br[q];
    #pragma unroll
    for (int j = 0; j < 4; ++j) {
      float dA = __expf(dv[j]*A);
      float Bm = Bp[(q*4+j)*XDIM];
      hs = fmaf(dA, hs, bv[j]*Bm);
      Pp *= dA;
    }
  }
  int ch = d*DSTATE + s;
  P[(size_t)c*NCH + ch] = Pp;
  S[(size_t)c*NCH + ch] = hs;
}

// Phase 2: serial combine over chunks -> incoming state per chunk.
__global__ __launch_bounds__(256) void k_scan_p2(const float* __restrict__ P,
    const float* __restrict__ S, float* __restrict__ hin) {
  int ch = blockIdx.x*256 + threadIdx.x;           // 0..NCH
  float Pv[NC], Sv[NC];
  #pragma unroll
  for (int c = 0; c < NC; ++c) {
    Pv[c] = P[(size_t)c*NCH + ch];
    Sv[c] = S[(size_t)c*NCH + ch];
  }
  float h = 0.f;
  #pragma unroll
  for (int c = 0; c < NC; ++c) {
    hin[(size_t)c*NCH + ch] = h;
    h = fmaf(Pv[c], h, Sv[c]);
  }
}

// Phase 3: re-scan each chunk from hin, emit gated output y[l][d].
__global__ __launch_bounds__(256) void k_scan_p3(const float* __restrict__ dT,
    const float* __restrict__ duT, const float* __restrict__ udT,
    const float* __restrict__ zT, const float* __restrict__ xdbl,
    const float* __restrict__ alog, const float* __restrict__ hin,
    float* __restrict__ y) {
  int tid = threadIdx.x;
  int s = tid & 15;
  int d = blockIdx.x*16 + (tid >> 4);
  int c = blockIdx.y;
  float A = -__expf(alog[d*DSTATE + s]);
  float hs = hin[(size_t)c*NCH + d*DSTATE + s];
  const float4* dr = reinterpret_cast<const float4*>(dT  + (size_t)d*SEQ + c*CHUNK);
  const float4* br = reinterpret_cast<const float4*>(duT + (size_t)d*SEQ + c*CHUNK);
  const float4* ur = reinterpret_cast<const float4*>(udT + (size_t)d*SEQ + c*CHUNK);
  const float4* zr = reinterpret_cast<const float4*>(zT  + (size_t)d*SEQ + c*CHUNK);
  const float* Bp = xdbl + (size_t)c*CHUNK*XDIM + DTRANK + s;
  const float* Cp = xdbl + (size_t)c*CHUNK*XDIM + DTRANK + DSTATE + s;
  for (int q = 0; q < CHUNK/4; ++q) {
    float dv[4], bv[4], uv[4], zv[4];
    *reinterpret_cast<float4*>(dv) = dr[q];
    *reinterpret_cast<float4*>(bv) = br[q];
    *reinterpret_cast<float4*>(uv) = ur[q];
    *reinterpret_cast<float4*>(zv) = zr[q];
    #pragma unroll
    for (int j = 0; j < 4; ++j) {
      float dA = __expf(dv[j]*A);
      float Bm = Bp[(q*4+j)*XDIM];
      float Cm = Cp[(q*4+j)*XDIM];
      hs = fmaf(dA, hs, bv[j]*Bm);
      float contrib = hs * Cm;
      contrib += __shfl_xor(contrib, 1);
      contrib += __shfl_xor(contrib, 2);
      contrib += __shfl_xor(contrib, 4);
      contrib += __shfl_xor(contrib, 8);
      if (s == 0) {
        int l = c*CHUNK + q*4 + j;
        float z = zv[j];
        float sz = z / (1.f + __expf(-z));
        y[(size_t)l*DINNER + d] = (contrib + uv[j]) * sz;
      }
    }
  }
}

// ---------------------------------------------------------------------------
// Per-row cross-entropy: rows 0..SEQ-2, target labels[row+1]
__global__ __launch_bounds__(256) void k_loss_row(const float* __restrict__ logits,
    const int* __restrict__ labels, float* __restrict__ rowloss) {
  int row = blockIdx.x;                            // 0 .. SEQ-2
  int tid = threadIdx.x;
  const float* lp = logits + (size_t)row*NVOCAB;
  float mx = -INFINITY;
  for (int i = tid; i < NVOCAB; i += 256) mx = fmaxf(mx, lp[i]);
  #pragma unroll
  for (int o = 32; o >= 1; o >>= 1) mx = fmaxf(mx, __shfl_xor(mx, o));
  __shared__ float sm[4];
  if ((tid & 63) == 0) sm[tid >> 6] = mx;
  __syncthreads();
  mx = fmaxf(fmaxf(sm[0], sm[1]), fmaxf(sm[2], sm[3]));
  float se = 0.f;
  for (int i = tid; i < NVOCAB; i += 256) se += expf(lp[i] - mx);
  #pragma unroll
  for (int o = 32; o >= 1; o >>= 1) se += __shfl_xor(se, o);
  __shared__ float ss[4];
  if ((tid & 63) == 0) ss[tid >> 6] = se;
  __syncthreads();
  if (tid == 0) {
    se = ss[0] + ss[1] + ss[2] + ss[3];
    int tgt = labels[row+1];
    float nll = 0.f;
    if (tgt != -100) nll = -(lp[tgt] - mx - logf(se));
    rowloss[row] = nll;
  }
}

__global__ __launch_bounds__(256) void k_loss_final(const float* __restrict__ rowloss,
    const int* __restrict__ labels, float* __restrict__ outloss) {
  int tid = threadIdx.x;
  float s = 0.f, cnt = 0.f;
  for (int i = tid; i < SEQ-1; i += 256) {
    s += rowloss[i];
    cnt += (labels[i+1] != -100) ? 1.f : 0.f;
  }
  #pragma unroll
  for (int o = 32; o >= 1; o >>= 1) { s += __shfl_xor(s, o); cnt += __shfl_xor(cnt, o); }
  __shared__ float sm[8];
  if ((tid & 63) == 0) { sm[tid >> 6] = s; sm[4 + (tid >> 6)] = cnt; }
  __syncthreads();
  if (tid == 0) {
    s   = sm[0] + sm[1] + sm[2] + sm[3];
    cnt = sm[4] + sm[5] + sm[6] + sm[7];
    outloss[0] = s / fmaxf(cnt, 1.f);
  }
}

// ---------------------------------------------------------------------------
extern "C" void kernel_launch(void* const* d_in, const int* in_sizes, int n_in,
                              void* d_out, int out_size, void* d_ws, size_t ws_size,
                              hipStream_t stream) {
  const int*   ids    = (const int*)  d_in[0];
  const int*   labels = (const int*)  d_in[1];
  const float* emb    = (const float*)d_in[2];
  const float* pos    = (const float*)d_in[3];
  const float* fnw    = (const float*)d_in[4];
  const float* nw     = (const float*)d_in[5];
  const float* iw     = (const float*)d_in[6];
  const float* cw     = (const float*)d_in[7];
  const float* cb     = (const float*)d_in[8];
  const float* xpw    = (const float*)d_in[9];
  const float* dtw    = (const float*)d_in[10];
  const float* dtb    = (const float*)d_in[11];
  const float* alog   = (const float*)d_in[12];
  const float* Dp     = (const float*)d_in[13];
  const float* ow     = (const float*)d_in[14];
  float* outp = (float*)d_out;

  // workspace layout (floats); every buffer fully rewritten each call.
  float* w = (float*)d_ws;
  float* h     = w; w += (size_t)SEQ*DMODEL;       // 1M
  float* x     = w; w += (size_t)SEQ*DMODEL;       // 1M
  float* xz    = w; w += (size_t)SEQ*2*DINNER;     // 4M
  float* u     = w; w += (size_t)SEQ*DINNER;       // 2M
  float* xdbl  = w; w += (size_t)SEQ*XDIM;         // 128K
  float* dT    = w; w += (size_t)SEQ*DINNER;       // 2M
  float* duT   = w; w += (size_t)SEQ*DINNER;       // 2M
  float* udT   = w; w += (size_t)SEQ*DINNER;       // 2M
  float* zT    = w; w += (size_t)SEQ*DINNER;       // 2M
  float* Pb    = w; w += (size_t)NC*NCH;           // 512K
  float* Sb    = w; w += (size_t)NC*NCH;           // 512K
  float* hinb  = w; w += (size_t)NC*NCH;           // 512K
  float* xwT   = w; w += (size_t)NLAYER*XDIM*DINNER;   // 512K
  float* dtwT  = w; w += (size_t)NLAYER*DTRANK*DINNER; // 256K
  float* rowl  = w; w += (size_t)SEQ;              // 2K   (~73 MB total)
  float* yb    = xz;  // y aliases xz: xz fully dead after k_delta_t

  k_embed<<<SEQ*DMODEL/256, 256, 0, stream>>>(ids, emb, pos, h);
  k_transpose_w_all<<<NLAYER*(XDIM*DINNER + DTRANK*DINNER)/256, 256, 0, stream>>>(
      xpw, dtw, xwT, dtwT);

  for (int i = 0; i < NLAYER; ++i) {
    k_rmsnorm<<<SEQ, 256, 0, stream>>>(h, nw + (size_t)i*DMODEL, x);
    gemm_nt<128,128,16,false><<<dim3(2*DINNER/128, SEQ/128), 256, 0, stream>>>(
        x, iw + (size_t)i*2*DINNER*DMODEL, xz, SEQ, 2*DINNER, DMODEL);
    k_conv_silu<<<SEQ*DINNER/256, 256, 0, stream>>>(
        xz, cw + (size_t)i*DINNER*4, cb + (size_t)i*DINNER, u);
    k_xproj<<<SEQ*64/256, 256, 0, stream>>>(
        u, xwT + (size_t)i*XDIM*DINNER, xdbl);
    k_delta_t<<<dim3(SEQ/32, DINNER/32), 256, 0, stream>>>(
        xdbl, dtwT + (size_t)i*DTRANK*DINNER, dtb + (size_t)i*DINNER,
        u, xz, Dp + (size_t)i*DINNER, dT, duT, udT, zT);
    k_scan_p1<<<dim3(DINNER/16, NC), 256, 0, stream>>>(
        dT, duT, xdbl, alog + (size_t)i*DINNER*DSTATE, Pb, Sb);
    k_scan_p2<<<NCH/256, 256, 0, stream>>>(Pb, Sb, hinb);
    k_scan_p3<<<dim3(DINNER/16, NC), 256, 0, stream>>>(
        dT, duT, udT, zT, xdbl, alog + (size_t)i*DINNER*DSTATE, hinb, yb);
    gemm_nt<64,64,32,true><<<dim3(DMODEL/64, SEQ/64), 256, 0, stream>>>(
        yb, ow + (size_t)i*DMODEL*DINNER, h, SEQ, DMODEL, DINNER);
  }

  k_rmsnorm<<<SEQ, 256, 0, stream>>>(h, fnw, x);
  gemm_nt<128,128,16,false><<<dim3(NVOCAB/128, SEQ/128), 256, 0, stream>>>(
      x, emb, outp, SEQ, NVOCAB, DMODEL);
  k_loss_row<<<SEQ-1, 256, 0, stream>>>(outp, labels, rowl);
  k_loss_final<<<1, 256, 0, stream>>>(rowl, labels, outp + (size_t)SEQ*NVOCAB);
}

// Round 8
// 1926.545 us; speedup vs baseline: 1.1554x; 1.1554x over previous
//
#include <hip/hip_runtime.h>
#include <math.h>

// Problem constants (from reference)
constexpr int SEQ   = 2048;   // L
constexpr int DMODEL= 512;
constexpr int NLAYER= 8;
constexpr int DSTATE= 16;
constexpr int DINNER= 1024;
constexpr int DTRANK= 32;
constexpr int NVOCAB= 4096;
constexpr int XDIM  = DTRANK + 2*DSTATE;  // 64
constexpr int NC    = 32;                 // scan sequence-chunks
constexpr int CHUNK = SEQ / NC;           // 64
constexpr int NCH   = DINNER * DSTATE;    // 16384 scan channels

typedef __bf16 bf16x8 __attribute__((ext_vector_type(8)));
typedef float  f32x4  __attribute__((ext_vector_type(4)));
typedef unsigned short u16x8 __attribute__((ext_vector_type(8)));
typedef unsigned short u16x4 __attribute__((ext_vector_type(4)));

__device__ __forceinline__ unsigned short f2bf(float f) {   // RNE f32 -> bf16
  unsigned u = __builtin_bit_cast(unsigned, f);
  return (unsigned short)((u + 0x7FFFu + ((u >> 16) & 1u)) >> 16);
}

// ---------------------------------------------------------------------------
// Embedding: h[l,d] = emb[ids[l],d] + pos[l,d]
__global__ __launch_bounds__(256) void k_embed(const int* __restrict__ ids,
    const float* __restrict__ emb, const float* __restrict__ pos,
    float* __restrict__ h) {
  int t = blockIdx.x*256 + threadIdx.x;           // over SEQ*DMODEL
  int l = t >> 9;                                  // /512
  int d = t & 511;
  h[t] = emb[(size_t)ids[l]*DMODEL + d] + pos[t];
}

// ---------------------------------------------------------------------------
// RMSNorm: one block per row of 512
__global__ __launch_bounds__(256) void k_rmsnorm(const float* __restrict__ in,
    const float* __restrict__ w, float* __restrict__ out) {
  int row = blockIdx.x;
  int tid = threadIdx.x;
  const float2* r = reinterpret_cast<const float2*>(in + (size_t)row*DMODEL);
  float2 v = r[tid];
  float ss = v.x*v.x + v.y*v.y;
  #pragma unroll
  for (int o = 32; o >= 1; o >>= 1) ss += __shfl_xor(ss, o);
  __shared__ float sm[4];
  if ((tid & 63) == 0) sm[tid >> 6] = ss;
  __syncthreads();
  float tot = sm[0] + sm[1] + sm[2] + sm[3];
  float scale = rsqrtf(tot * (1.0f/DMODEL) + 1e-6f);
  float2 wv = reinterpret_cast<const float2*>(w)[tid];
  float2 o2;
  o2.x = v.x * scale * wv.x;
  o2.y = v.y * scale * wv.y;
  reinterpret_cast<float2*>(out + (size_t)row*DMODEL)[tid] = o2;
}

// ---------------------------------------------------------------------------
// bf16 MFMA GEMM: C[M,N] (+)= A[M,K] * Bw[N,K]^T, f32 in/out, bf16 compute.
// 256 threads = 4 waves in 2x2; wave computes (BM/2)x(BN/2) via 16x16x32 MFMA.
// Reg-staged f32->bf16 RNE into padded LDS (row stride BK+8 u16 = 144B for
// BK=64: frag ds_read_b128 is 2-way-conflict max, which is free).
template<int BM, int BN, int BK, bool ACC>
__global__ __launch_bounds__(256) void mfma_gemm_nt(const float* __restrict__ A,
    const float* __restrict__ Bw, float* __restrict__ C,
    int M, int N, int K) {
  constexpr int LDA = BK + 8;             // u16 stride
  constexpr int WM = BM/2, WN = BN/2;
  constexpr int FM = WM/16, FN = WN/16;
  constexpr int KV = BK/4;                // float4 per row
  __shared__ unsigned short As[BM*LDA];
  __shared__ unsigned short Bs[BN*LDA];
  const int tid  = threadIdx.x;
  const int lane = tid & 63;
  const int l15  = lane & 15;
  const int kg   = lane >> 4;             // 0..3
  const int w    = tid >> 6;
  const int wr   = w >> 1, wc = w & 1;
  const int m0 = blockIdx.y * BM;
  const int n0 = blockIdx.x * BN;

  f32x4 acc[FM][FN];
  #pragma unroll
  for (int m = 0; m < FM; ++m)
    #pragma unroll
    for (int n = 0; n < FN; ++n)
      acc[m][n] = (f32x4){0.f, 0.f, 0.f, 0.f};

  for (int kt = 0; kt < K; kt += BK) {
    #pragma unroll
    for (int i = 0; i < BM*BK/4/256; ++i) {
      int idx = i*256 + tid;
      int row = idx / KV, v = idx % KV;
      float4 f = *reinterpret_cast<const float4*>(
          &A[(size_t)(m0+row)*K + kt + v*4]);
      u16x4 hh; hh[0]=f2bf(f.x); hh[1]=f2bf(f.y); hh[2]=f2bf(f.z); hh[3]=f2bf(f.w);
      *reinterpret_cast<u16x4*>(&As[row*LDA + v*4]) = hh;
    }
    #pragma unroll
    for (int i = 0; i < BN*BK/4/256; ++i) {
      int idx = i*256 + tid;
      int row = idx / KV, v = idx % KV;
      float4 f = *reinterpret_cast<const float4*>(
          &Bw[(size_t)(n0+row)*K + kt + v*4]);
      u16x4 hh; hh[0]=f2bf(f.x); hh[1]=f2bf(f.y); hh[2]=f2bf(f.z); hh[3]=f2bf(f.w);
      *reinterpret_cast<u16x4*>(&Bs[row*LDA + v*4]) = hh;
    }
    __syncthreads();

    #pragma unroll
    for (int ks = 0; ks < BK; ks += 32) {
      bf16x8 a[FM], b[FN];
      #pragma unroll
      for (int m = 0; m < FM; ++m)
        a[m] = __builtin_bit_cast(bf16x8, *reinterpret_cast<const u16x8*>(
            &As[(wr*WM + m*16 + l15)*LDA + ks + kg*8]));
      #pragma unroll
      for (int n = 0; n < FN; ++n)
        b[n] = __builtin_bit_cast(bf16x8, *reinterpret_cast<const u16x8*>(
            &Bs[(wc*WN + n*16 + l15)*LDA + ks + kg*8]));
      #pragma unroll
      for (int m = 0; m < FM; ++m)
        #pragma unroll
        for (int n = 0; n < FN; ++n)
          acc[m][n] = __builtin_amdgcn_mfma_f32_16x16x32_bf16(
              a[m], b[n], acc[m][n], 0, 0, 0);
    }
    __syncthreads();
  }

  // epilogue: C/D layout col = lane&15, row = (lane>>4)*4 + r   [m89-verified]
  #pragma unroll
  for (int m = 0; m < FM; ++m) {
    #pragma unroll
    for (int n = 0; n < FN; ++n) {
      int col = n0 + wc*WN + n*16 + l15;
      #pragma unroll
      for (int r = 0; r < 4; ++r) {
        int row = m0 + wr*WM + m*16 + kg*4 + r;
        float* p = &C[(size_t)row*N + col];
        if (ACC) *p += acc[m][n][r]; else *p = acc[m][n][r];
      }
    }
  }
}

// ---------------------------------------------------------------------------
// f32 tiled GEMM (kept for the output-facing logits matmul only).
template<int BM, int BN, int BK, bool ACC>
__global__ __launch_bounds__(256) void gemm_nt(const float* __restrict__ A,
    const float* __restrict__ Bw, float* __restrict__ C,
    int M, int N, int K) {
  constexpr int TM = BM/16, TN = BN/16;
  __shared__ float As[BK][BM+4];
  __shared__ float Bs[BK][BN+4];
  const int tid = threadIdx.x;
  const int tx = tid & 15, ty = tid >> 4;
  const int m0 = blockIdx.y * BM;
  const int n0 = blockIdx.x * BN;

  float acc[TM][TN];
  #pragma unroll
  for (int i = 0; i < TM; ++i)
    #pragma unroll
    for (int j = 0; j < TN; ++j) acc[i][j] = 0.f;

  for (int kt = 0; kt < K; kt += BK) {
    constexpr int A4 = BM*BK/4;
    #pragma unroll
    for (int i = 0; i < A4/256; ++i) {
      int idx = i*256 + tid;
      int row = idx / (BK/4);
      int v   = idx % (BK/4);
      float4 val = *reinterpret_cast<const float4*>(
          &A[(size_t)(m0+row)*K + kt + v*4]);
      As[v*4+0][row] = val.x;
      As[v*4+1][row] = val.y;
      As[v*4+2][row] = val.z;
      As[v*4+3][row] = val.w;
    }
    constexpr int B4 = BN*BK/4;
    #pragma unroll
    for (int i = 0; i < B4/256; ++i) {
      int idx = i*256 + tid;
      int row = idx / (BK/4);
      int v   = idx % (BK/4);
      float4 val = *reinterpret_cast<const float4*>(
          &Bw[(size_t)(n0+row)*K + kt + v*4]);
      Bs[v*4+0][row] = val.x;
      Bs[v*4+1][row] = val.y;
      Bs[v*4+2][row] = val.z;
      Bs[v*4+3][row] = val.w;
    }
    __syncthreads();

    #pragma unroll
    for (int k = 0; k < BK; ++k) {
      float a[TM], b[TN];
      #pragma unroll
      for (int i4 = 0; i4 < TM/4; ++i4) {
        float4 t4 = *reinterpret_cast<const float4*>(&As[k][ty*TM + i4*4]);
        a[i4*4+0] = t4.x; a[i4*4+1] = t4.y; a[i4*4+2] = t4.z; a[i4*4+3] = t4.w;
      }
      #pragma unroll
      for (int j4 = 0; j4 < TN/4; ++j4) {
        float4 t4 = *reinterpret_cast<const float4*>(&Bs[k][tx*TN + j4*4]);
        b[j4*4+0] = t4.x; b[j4*4+1] = t4.y; b[j4*4+2] = t4.z; b[j4*4+3] = t4.w;
      }
      #pragma unroll
      for (int i = 0; i < TM; ++i)
        #pragma unroll
        for (int j = 0; j < TN; ++j)
          acc[i][j] = fmaf(a[i], b[j], acc[i][j]);
    }
    __syncthreads();
  }

  #pragma unroll
  for (int i = 0; i < TM; ++i) {
    size_t row = (size_t)(m0 + ty*TM + i);
    float* crow = C + row*N + n0 + tx*TN;
    #pragma unroll
    for (int j4 = 0; j4 < TN/4; ++j4) {
      float4 v;
      if (ACC) {
        v = *reinterpret_cast<float4*>(&crow[j4*4]);
        v.x += acc[i][j4*4+0]; v.y += acc[i][j4*4+1];
        v.z += acc[i][j4*4+2]; v.w += acc[i][j4*4+3];
      } else {
        v = make_float4(acc[i][j4*4+0], acc[i][j4*4+1],
                        acc[i][j4*4+2], acc[i][j4*4+3]);
      }
      *reinterpret_cast<float4*>(&crow[j4*4]) = v;
    }
  }
}

// ---------------------------------------------------------------------------
// Depthwise causal conv (D_CONV=4) + bias + SiLU.  xi = xz[:, 0:DINNER]
__global__ __launch_bounds__(256) void k_conv_silu(const float* __restrict__ xz,
    const float* __restrict__ cw, const float* __restrict__ cb,
    float* __restrict__ u) {
  int t = blockIdx.x*256 + threadIdx.x;           // over SEQ*DINNER
  int l = t >> 10;
  int c = t & 1023;
  float4 w = reinterpret_cast<const float4*>(cw)[c];
  float acc = cb[c];
  const float* xi = xz + c;                        // row stride 2*DINNER
  if (l >= 3) acc = fmaf(xi[(size_t)(l-3)*2*DINNER], w.x, acc);
  if (l >= 2) acc = fmaf(xi[(size_t)(l-2)*2*DINNER], w.y, acc);
  if (l >= 1) acc = fmaf(xi[(size_t)(l-1)*2*DINNER], w.z, acc);
  acc = fmaf(xi[(size_t)l*2*DINNER], w.w, acc);
  u[t] = acc / (1.f + __expf(-acc));               // silu
}

// ---------------------------------------------------------------------------
// Transpose BOTH skinny weights for ALL layers in one dispatch.
__global__ __launch_bounds__(256) void k_transpose_w_all(
    const float* __restrict__ xw, const float* __restrict__ dw,
    float* __restrict__ xwT, float* __restrict__ dtwT) {
  constexpr int PER = XDIM*DINNER + DTRANK*DINNER;   // 98304 per layer
  int t = blockIdx.x*256 + threadIdx.x;
  int layer = t / PER;
  int r = t - layer*PER;
  if (r < XDIM*DINNER) {
    int k = r >> 6, e = r & 63;
    xwT[(size_t)layer*XDIM*DINNER + r] =
        xw[(size_t)layer*XDIM*DINNER + (size_t)e*DINNER + k];
  } else {
    int r2 = r - XDIM*DINNER;
    int k = r2 >> 10, d = r2 & 1023;
    dtwT[(size_t)layer*DTRANK*DINNER + r2] =
        dw[(size_t)layer*DINNER*DTRANK + (size_t)d*DTRANK + k];
  }
}

// ---------------------------------------------------------------------------
// x_proj: xdbl[l,e] = dot(u[l,:], xw[e,:])   (one wave per row, lane = e)
__global__ __launch_bounds__(256) void k_xproj(const float* __restrict__ u,
    const float* __restrict__ xwT, float* __restrict__ xdbl) {
  int gt = blockIdx.x*256 + threadIdx.x;
  int l = gt >> 6;
  int e = gt & 63;
  const float4* ur = reinterpret_cast<const float4*>(u + (size_t)l*DINNER);
  float acc = 0.f;
  #pragma unroll 4
  for (int k4 = 0; k4 < DINNER/4; ++k4) {
    float4 uu = ur[k4];                            // broadcast across wave
    const float* wp = xwT + k4*4*64 + e;           // coalesced across lanes
    acc = fmaf(uu.x, wp[0],   acc);
    acc = fmaf(uu.y, wp[64],  acc);
    acc = fmaf(uu.z, wp[128], acc);
    acc = fmaf(uu.w, wp[192], acc);
  }
  xdbl[gt] = acc;
}

// ---------------------------------------------------------------------------
// FUSED delta-projection + transpose.
__global__ __launch_bounds__(256) void k_delta_t(
    const float* __restrict__ xdbl, const float* __restrict__ dtwT,
    const float* __restrict__ db, const float* __restrict__ u,
    const float* __restrict__ xz, const float* __restrict__ Dp,
    float* __restrict__ dT, float* __restrict__ duT,
    float* __restrict__ udT, float* __restrict__ zT) {
  __shared__ float xs[32][33];   // xdbl[l][k], k = 0..31 (dt part)
  __shared__ float wt[32][33];   // dtwT[k][d]
  __shared__ float td[32][33];   // delta[l][d]
  __shared__ float tu[32][33];   // u[l][d]
  __shared__ float tz[32][33];   // z[l][d]
  int l0 = blockIdx.x*32, d0 = blockIdx.y*32;
  int tx = threadIdx.x & 31;
  int ty = threadIdx.x >> 5;     // 0..7
  #pragma unroll
  for (int j = 0; j < 32; j += 8) {
    int l = l0 + ty + j;
    xs[ty+j][tx] = xdbl[(size_t)l*XDIM + tx];
    wt[ty+j][tx] = dtwT[(size_t)(ty+j)*DINNER + d0 + tx];
    tu[ty+j][tx] = u[(size_t)l*DINNER + d0 + tx];
    tz[ty+j][tx] = xz[(size_t)l*2*DINNER + DINNER + d0 + tx];
  }
  __syncthreads();
  float bd = db[d0 + tx];
  #pragma unroll
  for (int j = 0; j < 32; j += 8) {
    int lr = ty + j;
    float acc = bd;
    #pragma unroll
    for (int k = 0; k < 32; ++k) acc = fmaf(xs[lr][k], wt[k][tx], acc);
    td[lr][tx] = (acc > 20.f) ? acc : log1pf(expf(acc));
  }
  __syncthreads();
  #pragma unroll
  for (int j = 0; j < 32; j += 8) {
    int d = d0 + ty + j, l = l0 + tx;
    float dv = td[tx][ty+j], uv = tu[tx][ty+j];
    size_t o = (size_t)d*SEQ + l;
    dT[o]  = dv;
    duT[o] = dv * uv;
    udT[o] = uv * Dp[d];
    zT[o]  = tz[tx][ty+j];
  }
}

// ---------------------------------------------------------------------------
// Chunked selective scan, phase 1.
__global__ __launch_bounds__(256) void k_scan_p1(const float* __restrict__ dT,
    const float* __restrict__ duT, const float* __restrict__ xdbl,
    const float* __restrict__ alog, float* __restrict__ P, float* __restrict__ S) {
  int tid = threadIdx.x;
  int s = tid & 15;
  int d = blockIdx.x*16 + (tid >> 4);
  int c = blockIdx.y;
  float A = -__expf(alog[d*DSTATE + s]);
  float hs = 0.f, Pp = 1.f;
  const float4* dr = reinterpret_cast<const float4*>(dT  + (size_t)d*SEQ + c*CHUNK);
  const float4* br = reinterpret_cast<const float4*>(duT + (size_t)d*SEQ + c*CHUNK);
  const float* Bp = xdbl + (size_t)c*CHUNK*XDIM + DTRANK + s;
  for (int q = 0; q < CHUNK/4; ++q) {
    float dv[4], bv[4];
    *reinterpret_cast<float4*>(dv) = dr[q];
    *reinterpret_cast<float4*>(bv) = br[q];
    #pragma unroll
    for (int j = 0; j < 4; ++j) {
      float dA = __expf(dv[j]*A);
      float Bm = Bp[(q*4+j)*XDIM];
      hs = fmaf(dA, hs, bv[j]*Bm);
      Pp *= dA;
    }
  }
  int ch = d*DSTATE + s;
  P[(size_t)c*NCH + ch] = Pp;
  S[(size_t)c*NCH + ch] = hs;
}

// Phase 2: serial combine over chunks -> incoming state per chunk.
__global__ __launch_bounds__(256) void k_scan_p2(const float* __restrict__ P,
    const float* __restrict__ S, float* __restrict__ hin) {
  int ch = blockIdx.x*256 + threadIdx.x;           // 0..NCH
  float Pv[NC], Sv[NC];
  #pragma unroll
  for (int c = 0; c < NC; ++c) {
    Pv[c] = P[(size_t)c*NCH + ch];
    Sv[c] = S[(size_t)c*NCH + ch];
  }
  float h = 0.f;
  #pragma unroll
  for (int c = 0; c < NC; ++c) {
    hin[(size_t)c*NCH + ch] = h;
    h = fmaf(Pv[c], h, Sv[c]);
  }
}

// Phase 3: re-scan each chunk from hin, emit gated output y[l][d].
__global__ __launch_bounds__(256) void k_scan_p3(const float* __restrict__ dT,
    const float* __restrict__ duT, const float* __restrict__ udT,
    const float* __restrict__ zT, const float* __restrict__ xdbl,
    const float* __restrict__ alog, const float* __restrict__ hin,
    float* __restrict__ y) {
  int tid = threadIdx.x;
  int s = tid & 15;
  int d = blockIdx.x*16 + (tid >> 4);
  int c = blockIdx.y;
  float A = -__expf(alog[d*DSTATE + s]);
  float hs = hin[(size_t)c*NCH + d*DSTATE + s];
  const float4* dr = reinterpret_cast<const float4*>(dT  + (size_t)d*SEQ + c*CHUNK);
  const float4* br = reinterpret_cast<const float4*>(duT + (size_t)d*SEQ + c*CHUNK);
  const float4* ur = reinterpret_cast<const float4*>(udT + (size_t)d*SEQ + c*CHUNK);
  const float4* zr = reinterpret_cast<const float4*>(zT  + (size_t)d*SEQ + c*CHUNK);
  const float* Bp = xdbl + (size_t)c*CHUNK*XDIM + DTRANK + s;
  const float* Cp = xdbl + (size_t)c*CHUNK*XDIM + DTRANK + DSTATE + s;
  for (int q = 0; q < CHUNK/4; ++q) {
    float dv[4], bv[4], uv[4], zv[4];
    *reinterpret_cast<float4*>(dv) = dr[q];
    *reinterpret_cast<float4*>(bv) = br[q];
    *reinterpret_cast<float4*>(uv) = ur[q];
    *reinterpret_cast<float4*>(zv) = zr[q];
    #pragma unroll
    for (int j = 0; j < 4; ++j) {
      float dA = __expf(dv[j]*A);
      float Bm = Bp[(q*4+j)*XDIM];
      float Cm = Cp[(q*4+j)*XDIM];
      hs = fmaf(dA, hs, bv[j]*Bm);
      float contrib = hs * Cm;
      contrib += __shfl_xor(contrib, 1);
      contrib += __shfl_xor(contrib, 2);
      contrib += __shfl_xor(contrib, 4);
      contrib += __shfl_xor(contrib, 8);
      if (s == 0) {
        int l = c*CHUNK + q*4 + j;
        float z = zv[j];
        float sz = z / (1.f + __expf(-z));
        y[(size_t)l*DINNER + d] = (contrib + uv[j]) * sz;
      }
    }
  }
}

// ---------------------------------------------------------------------------
// Per-row cross-entropy: rows 0..SEQ-2, target labels[row+1]
__global__ __launch_bounds__(256) void k_loss_row(const float* __restrict__ logits,
    const int* __restrict__ labels, float* __restrict__ rowloss) {
  int row = blockIdx.x;                            // 0 .. SEQ-2
  int tid = threadIdx.x;
  const float* lp = logits + (size_t)row*NVOCAB;
  float mx = -INFINITY;
  for (int i = tid; i < NVOCAB; i += 256) mx = fmaxf(mx, lp[i]);
  #pragma unroll
  for (int o = 32; o >= 1; o >>= 1) mx = fmaxf(mx, __shfl_xor(mx, o));
  __shared__ float sm[4];
  if ((tid & 63) == 0) sm[tid >> 6] = mx;
  __syncthreads();
  mx = fmaxf(fmaxf(sm[0], sm[1]), fmaxf(sm[2], sm[3]));
  float se = 0.f;
  for (int i = tid; i < NVOCAB; i += 256) se += expf(lp[i] - mx);
  #pragma unroll
  for (int o = 32; o >= 1; o >>= 1) se += __shfl_xor(se, o);
  __shared__ float ss[4];
  if ((tid & 63) == 0) ss[tid >> 6] = se;
  __syncthreads();
  if (tid == 0) {
    se = ss[0] + ss[1] + ss[2] + ss[3];
    int tgt = labels[row+1];
    float nll = 0.f;
    if (tgt != -100) nll = -(lp[tgt] - mx - logf(se));
    rowloss[row] = nll;
  }
}

__global__ __launch_bounds__(256) void k_loss_final(const float* __restrict__ rowloss,
    const int* __restrict__ labels, float* __restrict__ outloss) {
  int tid = threadIdx.x;
  float s = 0.f, cnt = 0.f;
  for (int i = tid; i < SEQ-1; i += 256) {
    s += rowloss[i];
    cnt += (labels[i+1] != -100) ? 1.f : 0.f;
  }
  #pragma unroll
  for (int o = 32; o >= 1; o >>= 1) { s += __shfl_xor(s, o); cnt += __shfl_xor(cnt, o); }
  __shared__ float sm[8];
  if ((tid & 63) == 0) { sm[tid >> 6] = s; sm[4 + (tid >> 6)] = cnt; }
  __syncthreads();
  if (tid == 0) {
    s   = sm[0] + sm[1] + sm[2] + sm[3];
    cnt = sm[4] + sm[5] + sm[6] + sm[7];
    outloss[0] = s / fmaxf(cnt, 1.f);
  }
}

// ---------------------------------------------------------------------------
extern "C" void kernel_launch(void* const* d_in, const int* in_sizes, int n_in,
                              void* d_out, int out_size, void* d_ws, size_t ws_size,
                              hipStream_t stream) {
  const int*   ids    = (const int*)  d_in[0];
  const int*   labels = (const int*)  d_in[1];
  const float* emb    = (const float*)d_in[2];
  const float* pos    = (const float*)d_in[3];
  const float* fnw    = (const float*)d_in[4];
  const float* nw     = (const float*)d_in[5];
  const float* iw     = (const float*)d_in[6];
  const float* cw     = (const float*)d_in[7];
  const float* cb     = (const float*)d_in[8];
  const float* xpw    = (const float*)d_in[9];
  const float* dtw    = (const float*)d_in[10];
  const float* dtb    = (const float*)d_in[11];
  const float* alog   = (const float*)d_in[12];
  const float* Dp     = (const float*)d_in[13];
  const float* ow     = (const float*)d_in[14];
  float* outp = (float*)d_out;

  // workspace layout (floats); every buffer fully rewritten each call.
  float* w = (float*)d_ws;
  float* h     = w; w += (size_t)SEQ*DMODEL;       // 1M
  float* x     = w; w += (size_t)SEQ*DMODEL;       // 1M
  float* xz    = w; w += (size_t)SEQ*2*DINNER;     // 4M
  float* u     = w; w += (size_t)SEQ*DINNER;       // 2M
  float* xdbl  = w; w += (size_t)SEQ*XDIM;         // 128K
  float* dT    = w; w += (size_t)SEQ*DINNER;       // 2M
  float* duT   = w; w += (size_t)SEQ*DINNER;       // 2M
  float* udT   = w; w += (size_t)SEQ*DINNER;       // 2M
  float* zT    = w; w += (size_t)SEQ*DINNER;       // 2M
  float* Pb    = w; w += (size_t)NC*NCH;           // 512K
  float* Sb    = w; w += (size_t)NC*NCH;           // 512K
  float* hinb  = w; w += (size_t)NC*NCH;           // 512K
  float* xwT   = w; w += (size_t)NLAYER*XDIM*DINNER;   // 512K
  float* dtwT  = w; w += (size_t)NLAYER*DTRANK*DINNER; // 256K
  float* rowl  = w; w += (size_t)SEQ;              // 2K   (~73 MB total)
  float* yb    = xz;  // y aliases xz: xz fully dead after k_delta_t

  k_embed<<<SEQ*DMODEL/256, 256, 0, stream>>>(ids, emb, pos, h);
  k_transpose_w_all<<<NLAYER*(XDIM*DINNER + DTRANK*DINNER)/256, 256, 0, stream>>>(
      xpw, dtw, xwT, dtwT);

  for (int i = 0; i < NLAYER; ++i) {
    k_rmsnorm<<<SEQ, 256, 0, stream>>>(h, nw + (size_t)i*DMODEL, x);
    mfma_gemm_nt<128,128,64,false><<<dim3(2*DINNER/128, SEQ/128), 256, 0, stream>>>(
        x, iw + (size_t)i*2*DINNER*DMODEL, xz, SEQ, 2*DINNER, DMODEL);
    k_conv_silu<<<SEQ*DINNER/256, 256, 0, stream>>>(
        xz, cw + (size_t)i*DINNER*4, cb + (size_t)i*DINNER, u);
    k_xproj<<<SEQ*64/256, 256, 0, stream>>>(
        u, xwT + (size_t)i*XDIM*DINNER, xdbl);
    k_delta_t<<<dim3(SEQ/32, DINNER/32), 256, 0, stream>>>(
        xdbl, dtwT + (size_t)i*DTRANK*DINNER, dtb + (size_t)i*DINNER,
        u, xz, Dp + (size_t)i*DINNER, dT, duT, udT, zT);
    k_scan_p1<<<dim3(DINNER/16, NC), 256, 0, stream>>>(
        dT, duT, xdbl, alog + (size_t)i*DINNER*DSTATE, Pb, Sb);
    k_scan_p2<<<NCH/256, 256, 0, stream>>>(Pb, Sb, hinb);
    k_scan_p3<<<dim3(DINNER/16, NC), 256, 0, stream>>>(
        dT, duT, udT, zT, xdbl, alog + (size_t)i*DINNER*DSTATE, hinb, yb);
    mfma_gemm_nt<64,64,64,true><<<dim3(DMODEL/64, SEQ/64), 256, 0, stream>>>(
        yb, ow + (size_t)i*DMODEL*DINNER, h, SEQ, DMODEL, DINNER);
  }

  k_rmsnorm<<<SEQ, 256, 0, stream>>>(h, fnw, x);
  gemm_nt<128,128,16,false><<<dim3(NVOCAB/128, SEQ/128), 256, 0, stream>>>(
      x, emb, outp, SEQ, NVOCAB, DMODEL);
  k_loss_row<<<SEQ-1, 256, 0, stream>>>(outp, labels, rowl);
  k_loss_final<<<1, 256, 0, stream>>>(rowl, labels, outp + (size_t)SEQ*NVOCAB);
}

// Round 9
// 1743.220 us; speedup vs baseline: 1.2769x; 1.1052x over previous
//
#include <hip/hip_runtime.h>
#include <math.h>

// Problem constants (from reference)
constexpr int SEQ   = 2048;   // L
constexpr int DMODEL= 512;
constexpr int NLAYER= 8;
constexpr int DSTATE= 16;
constexpr int DINNER= 1024;
constexpr int DTRANK= 32;
constexpr int NVOCAB= 4096;
constexpr int XDIM  = DTRANK + 2*DSTATE;  // 64
constexpr int NC    = 32;                 // scan sequence-chunks
constexpr int CHUNK = SEQ / NC;           // 64
constexpr int NCH   = DINNER * DSTATE;    // 16384 scan channels

typedef __bf16 bf16x8 __attribute__((ext_vector_type(8)));
typedef float  f32x4  __attribute__((ext_vector_type(4)));
typedef unsigned short u16x8 __attribute__((ext_vector_type(8)));
typedef unsigned short u16x4 __attribute__((ext_vector_type(4)));

__device__ __forceinline__ unsigned short f2bf(float f) {   // RNE f32 -> bf16
  unsigned u = __builtin_bit_cast(unsigned, f);
  return (unsigned short)((u + 0x7FFFu + ((u >> 16) & 1u)) >> 16);
}

// ---------------------------------------------------------------------------
// Embedding: h[l,d] = emb[ids[l],d] + pos[l,d]
__global__ __launch_bounds__(256) void k_embed(const int* __restrict__ ids,
    const float* __restrict__ emb, const float* __restrict__ pos,
    float* __restrict__ h) {
  int t = blockIdx.x*256 + threadIdx.x;           // over SEQ*DMODEL
  int l = t >> 9;                                  // /512
  int d = t & 511;
  h[t] = emb[(size_t)ids[l]*DMODEL + d] + pos[t];
}

// ---------------------------------------------------------------------------
// RMSNorm: one block per row of 512
__global__ __launch_bounds__(256) void k_rmsnorm(const float* __restrict__ in,
    const float* __restrict__ w, float* __restrict__ out) {
  int row = blockIdx.x;
  int tid = threadIdx.x;
  const float2* r = reinterpret_cast<const float2*>(in + (size_t)row*DMODEL);
  float2 v = r[tid];
  float ss = v.x*v.x + v.y*v.y;
  #pragma unroll
  for (int o = 32; o >= 1; o >>= 1) ss += __shfl_xor(ss, o);
  __shared__ float sm[4];
  if ((tid & 63) == 0) sm[tid >> 6] = ss;
  __syncthreads();
  float tot = sm[0] + sm[1] + sm[2] + sm[3];
  float scale = rsqrtf(tot * (1.0f/DMODEL) + 1e-6f);
  float2 wv = reinterpret_cast<const float2*>(w)[tid];
  float2 o2;
  o2.x = v.x * scale * wv.x;
  o2.y = v.y * scale * wv.y;
  reinterpret_cast<float2*>(out + (size_t)row*DMODEL)[tid] = o2;
}

// ---------------------------------------------------------------------------
// bf16 MFMA GEMM: C[M,N] (+)= A[M,K] * Bw[N,K]^T, f32 in/out, bf16 compute.
// 256 threads = 4 waves in 2x2; wave computes (BM/2)x(BN/2) via 16x16x32 MFMA.
// TILED FOR OCCUPANCY: grid must be >= 512 blocks (>=2 blocks/CU) so each
// SIMD holds >=2 waves — round-8 counters showed 1 wave/SIMD fully exposes
// the staging-latency + barrier stalls (mfma ~= f32 at 1 block/CU; logits
// f32 at 2 blocks/CU did 2x the work in the same time).
template<int BM, int BN, int BK, bool ACC>
__global__ __launch_bounds__(256) void mfma_gemm_nt(const float* __restrict__ A,
    const float* __restrict__ Bw, float* __restrict__ C,
    int M, int N, int K) {
  constexpr int LDA = BK + 8;             // u16 stride
  constexpr int WM = BM/2, WN = BN/2;
  constexpr int FM = WM/16, FN = WN/16;
  constexpr int KV = BK/4;                // float4 per row
  __shared__ unsigned short As[BM*LDA];
  __shared__ unsigned short Bs[BN*LDA];
  const int tid  = threadIdx.x;
  const int lane = tid & 63;
  const int l15  = lane & 15;
  const int kg   = lane >> 4;             // 0..3
  const int w    = tid >> 6;
  const int wr   = w >> 1, wc = w & 1;
  const int m0 = blockIdx.y * BM;
  const int n0 = blockIdx.x * BN;

  f32x4 acc[FM][FN];
  #pragma unroll
  for (int m = 0; m < FM; ++m)
    #pragma unroll
    for (int n = 0; n < FN; ++n)
      acc[m][n] = (f32x4){0.f, 0.f, 0.f, 0.f};

  for (int kt = 0; kt < K; kt += BK) {
    #pragma unroll
    for (int i = 0; i < BM*BK/4/256; ++i) {
      int idx = i*256 + tid;
      int row = idx / KV, v = idx % KV;
      float4 f = *reinterpret_cast<const float4*>(
          &A[(size_t)(m0+row)*K + kt + v*4]);
      u16x4 hh; hh[0]=f2bf(f.x); hh[1]=f2bf(f.y); hh[2]=f2bf(f.z); hh[3]=f2bf(f.w);
      *reinterpret_cast<u16x4*>(&As[row*LDA + v*4]) = hh;
    }
    #pragma unroll
    for (int i = 0; i < BN*BK/4/256; ++i) {
      int idx = i*256 + tid;
      int row = idx / KV, v = idx % KV;
      float4 f = *reinterpret_cast<const float4*>(
          &Bw[(size_t)(n0+row)*K + kt + v*4]);
      u16x4 hh; hh[0]=f2bf(f.x); hh[1]=f2bf(f.y); hh[2]=f2bf(f.z); hh[3]=f2bf(f.w);
      *reinterpret_cast<u16x4*>(&Bs[row*LDA + v*4]) = hh;
    }
    __syncthreads();

    #pragma unroll
    for (int ks = 0; ks < BK; ks += 32) {
      bf16x8 a[FM], b[FN];
      #pragma unroll
      for (int m = 0; m < FM; ++m)
        a[m] = __builtin_bit_cast(bf16x8, *reinterpret_cast<const u16x8*>(
            &As[(wr*WM + m*16 + l15)*LDA + ks + kg*8]));
      #pragma unroll
      for (int n = 0; n < FN; ++n)
        b[n] = __builtin_bit_cast(bf16x8, *reinterpret_cast<const u16x8*>(
            &Bs[(wc*WN + n*16 + l15)*LDA + ks + kg*8]));
      #pragma unroll
      for (int m = 0; m < FM; ++m)
        #pragma unroll
        for (int n = 0; n < FN; ++n)
          acc[m][n] = __builtin_amdgcn_mfma_f32_16x16x32_bf16(
              a[m], b[n], acc[m][n], 0, 0, 0);
    }
    __syncthreads();
  }

  // epilogue: C/D layout col = lane&15, row = (lane>>4)*4 + r   [m89-verified]
  #pragma unroll
  for (int m = 0; m < FM; ++m) {
    #pragma unroll
    for (int n = 0; n < FN; ++n) {
      int col = n0 + wc*WN + n*16 + l15;
      #pragma unroll
      for (int r = 0; r < 4; ++r) {
        int row = m0 + wr*WM + m*16 + kg*4 + r;
        float* p = &C[(size_t)row*N + col];
        if (ACC) *p += acc[m][n][r]; else *p = acc[m][n][r];
      }
    }
  }
}

// ---------------------------------------------------------------------------
// f32 tiled GEMM — retained as fallback (no instantiation => no codegen).
template<int BM, int BN, int BK, bool ACC>
__global__ __launch_bounds__(256) void gemm_nt(const float* __restrict__ A,
    const float* __restrict__ Bw, float* __restrict__ C,
    int M, int N, int K) {
  constexpr int TM = BM/16, TN = BN/16;
  __shared__ float As[BK][BM+4];
  __shared__ float Bs[BK][BN+4];
  const int tid = threadIdx.x;
  const int tx = tid & 15, ty = tid >> 4;
  const int m0 = blockIdx.y * BM;
  const int n0 = blockIdx.x * BN;

  float acc[TM][TN];
  #pragma unroll
  for (int i = 0; i < TM; ++i)
    #pragma unroll
    for (int j = 0; j < TN; ++j) acc[i][j] = 0.f;

  for (int kt = 0; kt < K; kt += BK) {
    constexpr int A4 = BM*BK/4;
    #pragma unroll
    for (int i = 0; i < A4/256; ++i) {
      int idx = i*256 + tid;
      int row = idx / (BK/4);
      int v   = idx % (BK/4);
      float4 val = *reinterpret_cast<const float4*>(
          &A[(size_t)(m0+row)*K + kt + v*4]);
      As[v*4+0][row] = val.x;
      As[v*4+1][row] = val.y;
      As[v*4+2][row] = val.z;
      As[v*4+3][row] = val.w;
    }
    constexpr int B4 = BN*BK/4;
    #pragma unroll
    for (int i = 0; i < B4/256; ++i) {
      int idx = i*256 + tid;
      int row = idx / (BK/4);
      int v   = idx % (BK/4);
      float4 val = *reinterpret_cast<const float4*>(
          &Bw[(size_t)(n0+row)*K + kt + v*4]);
      Bs[v*4+0][row] = val.x;
      Bs[v*4+1][row] = val.y;
      Bs[v*4+2][row] = val.z;
      Bs[v*4+3][row] = val.w;
    }
    __syncthreads();

    #pragma unroll
    for (int k = 0; k < BK; ++k) {
      float a[TM], b[TN];
      #pragma unroll
      for (int i4 = 0; i4 < TM/4; ++i4) {
        float4 t4 = *reinterpret_cast<const float4*>(&As[k][ty*TM + i4*4]);
        a[i4*4+0] = t4.x; a[i4*4+1] = t4.y; a[i4*4+2] = t4.z; a[i4*4+3] = t4.w;
      }
      #pragma unroll
      for (int j4 = 0; j4 < TN/4; ++j4) {
        float4 t4 = *reinterpret_cast<const float4*>(&Bs[k][tx*TN + j4*4]);
        b[j4*4+0] = t4.x; b[j4*4+1] = t4.y; b[j4*4+2] = t4.z; b[j4*4+3] = t4.w;
      }
      #pragma unroll
      for (int i = 0; i < TM; ++i)
        #pragma unroll
        for (int j = 0; j < TN; ++j)
          acc[i][j] = fmaf(a[i], b[j], acc[i][j]);
    }
    __syncthreads();
  }

  #pragma unroll
  for (int i = 0; i < TM; ++i) {
    size_t row = (size_t)(m0 + ty*TM + i);
    float* crow = C + row*N + n0 + tx*TN;
    #pragma unroll
    for (int j4 = 0; j4 < TN/4; ++j4) {
      float4 v;
      if (ACC) {
        v = *reinterpret_cast<float4*>(&crow[j4*4]);
        v.x += acc[i][j4*4+0]; v.y += acc[i][j4*4+1];
        v.z += acc[i][j4*4+2]; v.w += acc[i][j4*4+3];
      } else {
        v = make_float4(acc[i][j4*4+0], acc[i][j4*4+1],
                        acc[i][j4*4+2], acc[i][j4*4+3]);
      }
      *reinterpret_cast<float4*>(&crow[j4*4]) = v;
    }
  }
}

// ---------------------------------------------------------------------------
// Depthwise causal conv (D_CONV=4) + bias + SiLU.  xi = xz[:, 0:DINNER]
__global__ __launch_bounds__(256) void k_conv_silu(const float* __restrict__ xz,
    const float* __restrict__ cw, const float* __restrict__ cb,
    float* __restrict__ u) {
  int t = blockIdx.x*256 + threadIdx.x;           // over SEQ*DINNER
  int l = t >> 10;
  int c = t & 1023;
  float4 w = reinterpret_cast<const float4*>(cw)[c];
  float acc = cb[c];
  const float* xi = xz + c;                        // row stride 2*DINNER
  if (l >= 3) acc = fmaf(xi[(size_t)(l-3)*2*DINNER], w.x, acc);
  if (l >= 2) acc = fmaf(xi[(size_t)(l-2)*2*DINNER], w.y, acc);
  if (l >= 1) acc = fmaf(xi[(size_t)(l-1)*2*DINNER], w.z, acc);
  acc = fmaf(xi[(size_t)l*2*DINNER], w.w, acc);
  u[t] = acc / (1.f + __expf(-acc));               // silu
}

// ---------------------------------------------------------------------------
// Transpose BOTH skinny weights for ALL layers in one dispatch.
__global__ __launch_bounds__(256) void k_transpose_w_all(
    const float* __restrict__ xw, const float* __restrict__ dw,
    float* __restrict__ xwT, float* __restrict__ dtwT) {
  constexpr int PER = XDIM*DINNER + DTRANK*DINNER;   // 98304 per layer
  int t = blockIdx.x*256 + threadIdx.x;
  int layer = t / PER;
  int r = t - layer*PER;
  if (r < XDIM*DINNER) {
    int k = r >> 6, e = r & 63;
    xwT[(size_t)layer*XDIM*DINNER + r] =
        xw[(size_t)layer*XDIM*DINNER + (size_t)e*DINNER + k];
  } else {
    int r2 = r - XDIM*DINNER;
    int k = r2 >> 10, d = r2 & 1023;
    dtwT[(size_t)layer*DTRANK*DINNER + r2] =
        dw[(size_t)layer*DINNER*DTRANK + (size_t)d*DTRANK + k];
  }
}

// ---------------------------------------------------------------------------
// x_proj: xdbl[l,e] = dot(u[l,:], xw[e,:])   (one wave per row, lane = e)
__global__ __launch_bounds__(256) void k_xproj(const float* __restrict__ u,
    const float* __restrict__ xwT, float* __restrict__ xdbl) {
  int gt = blockIdx.x*256 + threadIdx.x;
  int l = gt >> 6;
  int e = gt & 63;
  const float4* ur = reinterpret_cast<const float4*>(u + (size_t)l*DINNER);
  float acc = 0.f;
  #pragma unroll 4
  for (int k4 = 0; k4 < DINNER/4; ++k4) {
    float4 uu = ur[k4];                            // broadcast across wave
    const float* wp = xwT + k4*4*64 + e;           // coalesced across lanes
    acc = fmaf(uu.x, wp[0],   acc);
    acc = fmaf(uu.y, wp[64],  acc);
    acc = fmaf(uu.z, wp[128], acc);
    acc = fmaf(uu.w, wp[192], acc);
  }
  xdbl[gt] = acc;
}

// ---------------------------------------------------------------------------
// FUSED delta-projection + transpose.
__global__ __launch_bounds__(256) void k_delta_t(
    const float* __restrict__ xdbl, const float* __restrict__ dtwT,
    const float* __restrict__ db, const float* __restrict__ u,
    const float* __restrict__ xz, const float* __restrict__ Dp,
    float* __restrict__ dT, float* __restrict__ duT,
    float* __restrict__ udT, float* __restrict__ zT) {
  __shared__ float xs[32][33];   // xdbl[l][k], k = 0..31 (dt part)
  __shared__ float wt[32][33];   // dtwT[k][d]
  __shared__ float td[32][33];   // delta[l][d]
  __shared__ float tu[32][33];   // u[l][d]
  __shared__ float tz[32][33];   // z[l][d]
  int l0 = blockIdx.x*32, d0 = blockIdx.y*32;
  int tx = threadIdx.x & 31;
  int ty = threadIdx.x >> 5;     // 0..7
  #pragma unroll
  for (int j = 0; j < 32; j += 8) {
    int l = l0 + ty + j;
    xs[ty+j][tx] = xdbl[(size_t)l*XDIM + tx];
    wt[ty+j][tx] = dtwT[(size_t)(ty+j)*DINNER + d0 + tx];
    tu[ty+j][tx] = u[(size_t)l*DINNER + d0 + tx];
    tz[ty+j][tx] = xz[(size_t)l*2*DINNER + DINNER + d0 + tx];
  }
  __syncthreads();
  float bd = db[d0 + tx];
  #pragma unroll
  for (int j = 0; j < 32; j += 8) {
    int lr = ty + j;
    float acc = bd;
    #pragma unroll
    for (int k = 0; k < 32; ++k) acc = fmaf(xs[lr][k], wt[k][tx], acc);
    td[lr][tx] = (acc > 20.f) ? acc : log1pf(expf(acc));
  }
  __syncthreads();
  #pragma unroll
  for (int j = 0; j < 32; j += 8) {
    int d = d0 + ty + j, l = l0 + tx;
    float dv = td[tx][ty+j], uv = tu[tx][ty+j];
    size_t o = (size_t)d*SEQ + l;
    dT[o]  = dv;
    duT[o] = dv * uv;
    udT[o] = uv * Dp[d];
    zT[o]  = tz[tx][ty+j];
  }
}

// ---------------------------------------------------------------------------
// Chunked selective scan, phase 1.
__global__ __launch_bounds__(256) void k_scan_p1(const float* __restrict__ dT,
    const float* __restrict__ duT, const float* __restrict__ xdbl,
    const float* __restrict__ alog, float* __restrict__ P, float* __restrict__ S) {
  int tid = threadIdx.x;
  int s = tid & 15;
  int d = blockIdx.x*16 + (tid >> 4);
  int c = blockIdx.y;
  float A = -__expf(alog[d*DSTATE + s]);
  float hs = 0.f, Pp = 1.f;
  const float4* dr = reinterpret_cast<const float4*>(dT  + (size_t)d*SEQ + c*CHUNK);
  const float4* br = reinterpret_cast<const float4*>(duT + (size_t)d*SEQ + c*CHUNK);
  const float* Bp = xdbl + (size_t)c*CHUNK*XDIM + DTRANK + s;
  for (int q = 0; q < CHUNK/4; ++q) {
    float dv[4], bv[4];
    *reinterpret_cast<float4*>(dv) = dr[q];
    *reinterpret_cast<float4*>(bv) = br[q];
    #pragma unroll
    for (int j = 0; j < 4; ++j) {
      float dA = __expf(dv[j]*A);
      float Bm = Bp[(q*4+j)*XDIM];
      hs = fmaf(dA, hs, bv[j]*Bm);
      Pp *= dA;
    }
  }
  int ch = d*DSTATE + s;
  P[(size_t)c*NCH + ch] = Pp;
  S[(size_t)c*NCH + ch] = hs;
}

// Phase 2: serial combine over chunks -> incoming state per chunk.
__global__ __launch_bounds__(256) void k_scan_p2(const float* __restrict__ P,
    const float* __restrict__ S, float* __restrict__ hin) {
  int ch = blockIdx.x*256 + threadIdx.x;           // 0..NCH
  float Pv[NC], Sv[NC];
  #pragma unroll
  for (int c = 0; c < NC; ++c) {
    Pv[c] = P[(size_t)c*NCH + ch];
    Sv[c] = S[(size_t)c*NCH + ch];
  }
  float h = 0.f;
  #pragma unroll
  for (int c = 0; c < NC; ++c) {
    hin[(size_t)c*NCH + ch] = h;
    h = fmaf(Pv[c], h, Sv[c]);
  }
}

// Phase 3: re-scan each chunk from hin, emit gated output y[l][d].
__global__ __launch_bounds__(256) void k_scan_p3(const float* __restrict__ dT,
    const float* __restrict__ duT, const float* __restrict__ udT,
    const float* __restrict__ zT, const float* __restrict__ xdbl,
    const float* __restrict__ alog, const float* __restrict__ hin,
    float* __restrict__ y) {
  int tid = threadIdx.x;
  int s = tid & 15;
  int d = blockIdx.x*16 + (tid >> 4);
  int c = blockIdx.y;
  float A = -__expf(alog[d*DSTATE + s]);
  float hs = hin[(size_t)c*NCH + d*DSTATE + s];
  const float4* dr = reinterpret_cast<const float4*>(dT  + (size_t)d*SEQ + c*CHUNK);
  const float4* br = reinterpret_cast<const float4*>(duT + (size_t)d*SEQ + c*CHUNK);
  const float4* ur = reinterpret_cast<const float4*>(udT + (size_t)d*SEQ + c*CHUNK);
  const float4* zr = reinterpret_cast<const float4*>(zT  + (size_t)d*SEQ + c*CHUNK);
  const float* Bp = xdbl + (size_t)c*CHUNK*XDIM + DTRANK + s;
  const float* Cp = xdbl + (size_t)c*CHUNK*XDIM + DTRANK + DSTATE + s;
  for (int q = 0; q < CHUNK/4; ++q) {
    float dv[4], bv[4], uv[4], zv[4];
    *reinterpret_cast<float4*>(dv) = dr[q];
    *reinterpret_cast<float4*>(bv) = br[q];
    *reinterpret_cast<float4*>(uv) = ur[q];
    *reinterpret_cast<float4*>(zv) = zr[q];
    #pragma unroll
    for (int j = 0; j < 4; ++j) {
      float dA = __expf(dv[j]*A);
      float Bm = Bp[(q*4+j)*XDIM];
      float Cm = Cp[(q*4+j)*XDIM];
      hs = fmaf(dA, hs, bv[j]*Bm);
      float contrib = hs * Cm;
      contrib += __shfl_xor(contrib, 1);
      contrib += __shfl_xor(contrib, 2);
      contrib += __shfl_xor(contrib, 4);
      contrib += __shfl_xor(contrib, 8);
      if (s == 0) {
        int l = c*CHUNK + q*4 + j;
        float z = zv[j];
        float sz = z / (1.f + __expf(-z));
        y[(size_t)l*DINNER + d] = (contrib + uv[j]) * sz;
      }
    }
  }
}

// ---------------------------------------------------------------------------
// Per-row cross-entropy: rows 0..SEQ-2, target labels[row+1]
__global__ __launch_bounds__(256) void k_loss_row(const float* __restrict__ logits,
    const int* __restrict__ labels, float* __restrict__ rowloss) {
  int row = blockIdx.x;                            // 0 .. SEQ-2
  int tid = threadIdx.x;
  const float* lp = logits + (size_t)row*NVOCAB;
  float mx = -INFINITY;
  for (int i = tid; i < NVOCAB; i += 256) mx = fmaxf(mx, lp[i]);
  #pragma unroll
  for (int o = 32; o >= 1; o >>= 1) mx = fmaxf(mx, __shfl_xor(mx, o));
  __shared__ float sm[4];
  if ((tid & 63) == 0) sm[tid >> 6] = mx;
  __syncthreads();
  mx = fmaxf(fmaxf(sm[0], sm[1]), fmaxf(sm[2], sm[3]));
  float se = 0.f;
  for (int i = tid; i < NVOCAB; i += 256) se += expf(lp[i] - mx);
  #pragma unroll
  for (int o = 32; o >= 1; o >>= 1) se += __shfl_xor(se, o);
  __shared__ float ss[4];
  if ((tid & 63) == 0) ss[tid >> 6] = se;
  __syncthreads();
  if (tid == 0) {
    se = ss[0] + ss[1] + ss[2] + ss[3];
    int tgt = labels[row+1];
    float nll = 0.f;
    if (tgt != -100) nll = -(lp[tgt] - mx - logf(se));
    rowloss[row] = nll;
  }
}

__global__ __launch_bounds__(256) void k_loss_final(const float* __restrict__ rowloss,
    const int* __restrict__ labels, float* __restrict__ outloss) {
  int tid = threadIdx.x;
  float s = 0.f, cnt = 0.f;
  for (int i = tid; i < SEQ-1; i += 256) {
    s += rowloss[i];
    cnt += (labels[i+1] != -100) ? 1.f : 0.f;
  }
  #pragma unroll
  for (int o = 32; o >= 1; o >>= 1) { s += __shfl_xor(s, o); cnt += __shfl_xor(cnt, o); }
  __shared__ float sm[8];
  if ((tid & 63) == 0) { sm[tid >> 6] = s; sm[4 + (tid >> 6)] = cnt; }
  __syncthreads();
  if (tid == 0) {
    s   = sm[0] + sm[1] + sm[2] + sm[3];
    cnt = sm[4] + sm[5] + sm[6] + sm[7];
    outloss[0] = s / fmaxf(cnt, 1.f);
  }
}

// ---------------------------------------------------------------------------
extern "C" void kernel_launch(void* const* d_in, const int* in_sizes, int n_in,
                              void* d_out, int out_size, void* d_ws, size_t ws_size,
                              hipStream_t stream) {
  const int*   ids    = (const int*)  d_in[0];
  const int*   labels = (const int*)  d_in[1];
  const float* emb    = (const float*)d_in[2];
  const float* pos    = (const float*)d_in[3];
  const float* fnw    = (const float*)d_in[4];
  const float* nw     = (const float*)d_in[5];
  const float* iw     = (const float*)d_in[6];
  const float* cw     = (const float*)d_in[7];
  const float* cb     = (const float*)d_in[8];
  const float* xpw    = (const float*)d_in[9];
  const float* dtw    = (const float*)d_in[10];
  const float* dtb    = (const float*)d_in[11];
  const float* alog   = (const float*)d_in[12];
  const float* Dp     = (const float*)d_in[13];
  const float* ow     = (const float*)d_in[14];
  float* outp = (float*)d_out;

  // workspace layout (floats); every buffer fully rewritten each call.
  float* w = (float*)d_ws;
  float* h     = w; w += (size_t)SEQ*DMODEL;       // 1M
  float* x     = w; w += (size_t)SEQ*DMODEL;       // 1M
  float* xz    = w; w += (size_t)SEQ*2*DINNER;     // 4M
  float* u     = w; w += (size_t)SEQ*DINNER;       // 2M
  float* xdbl  = w; w += (size_t)SEQ*XDIM;         // 128K
  float* dT    = w; w += (size_t)SEQ*DINNER;       // 2M
  float* duT   = w; w += (size_t)SEQ*DINNER;       // 2M
  float* udT   = w; w += (size_t)SEQ*DINNER;       // 2M
  float* zT    = w; w += (size_t)SEQ*DINNER;       // 2M
  float* Pb    = w; w += (size_t)NC*NCH;           // 512K
  float* Sb    = w; w += (size_t)NC*NCH;           // 512K
  float* hinb  = w; w += (size_t)NC*NCH;           // 512K
  float* xwT   = w; w += (size_t)NLAYER*XDIM*DINNER;   // 512K
  float* dtwT  = w; w += (size_t)NLAYER*DTRANK*DINNER; // 256K
  float* rowl  = w; w += (size_t)SEQ;              // 2K   (~73 MB total)
  float* yb    = xz;  // y aliases xz: xz fully dead after k_delta_t

  k_embed<<<SEQ*DMODEL/256, 256, 0, stream>>>(ids, emb, pos, h);
  k_transpose_w_all<<<NLAYER*(XDIM*DINNER + DTRANK*DINNER)/256, 256, 0, stream>>>(
      xpw, dtw, xwT, dtwT);

  for (int i = 0; i < NLAYER; ++i) {
    k_rmsnorm<<<SEQ, 256, 0, stream>>>(h, nw + (size_t)i*DMODEL, x);
    // 64x128 tile: grid (16,32)=512 blocks -> 2 blocks/CU, 2 waves/SIMD.
    mfma_gemm_nt<64,128,64,false><<<dim3(2*DINNER/128, SEQ/64), 256, 0, stream>>>(
        x, iw + (size_t)i*2*DINNER*DMODEL, xz, SEQ, 2*DINNER, DMODEL);
    k_conv_silu<<<SEQ*DINNER/256, 256, 0, stream>>>(
        xz, cw + (size_t)i*DINNER*4, cb + (size_t)i*DINNER, u);
    k_xproj<<<SEQ*64/256, 256, 0, stream>>>(
        u, xwT + (size_t)i*XDIM*DINNER, xdbl);
    k_delta_t<<<dim3(SEQ/32, DINNER/32), 256, 0, stream>>>(
        xdbl, dtwT + (size_t)i*DTRANK*DINNER, dtb + (size_t)i*DINNER,
        u, xz, Dp + (size_t)i*DINNER, dT, duT, udT, zT);
    k_scan_p1<<<dim3(DINNER/16, NC), 256, 0, stream>>>(
        dT, duT, xdbl, alog + (size_t)i*DINNER*DSTATE, Pb, Sb);
    k_scan_p2<<<NCH/256, 256, 0, stream>>>(Pb, Sb, hinb);
    k_scan_p3<<<dim3(DINNER/16, NC), 256, 0, stream>>>(
        dT, duT, udT, zT, xdbl, alog + (size_t)i*DINNER*DSTATE, hinb, yb);
    // 32x64 tile: grid (8,64)=512 blocks -> 2 blocks/CU.
    mfma_gemm_nt<32,64,64,true><<<dim3(DMODEL/64, SEQ/32), 256, 0, stream>>>(
        yb, ow + (size_t)i*DMODEL*DINNER, h, SEQ, DMODEL, DINNER);
  }

  k_rmsnorm<<<SEQ, 256, 0, stream>>>(h, fnw, x);
  // logits now bf16 MFMA: 64x128 tile, grid (32,32)=1024 blocks -> 4 blocks/CU.
  mfma_gemm_nt<64,128,64,false><<<dim3(NVOCAB/128, SEQ/64), 256, 0, stream>>>(
      x, emb, outp, SEQ, NVOCAB, DMODEL);
  k_loss_row<<<SEQ-1, 256, 0, stream>>>(outp, labels, rowl);
  k_loss_final<<<1, 256, 0, stream>>>(rowl, labels, outp + (size_t)SEQ*NVOCAB);
}